// Round 2
// 172.954 us; speedup vs baseline: 1.2664x; 1.2664x over previous
//
#include <hip/hip_runtime.h>
#include <cstdint>

#define BB 2
#define NN 16384
#define MM 4096
#define CF 256
#define CT 128
#define CP 64

// ======================= kernel 1: 3-NN -> workspace =======================
// Round-7 proven scan geometry (8 lanes/query, 2048-ref LDS chunks, bit-exact
// pre-doubled refs) + NEW: wave-uniform branchy top-3 update gated by a shared
// pruning threshold tau (min of the 8 lanes' d2v, refreshed every 32 iters).
// Pruning dd >= tau is exact: tau is some lane's 3rd-smallest of genuinely
// seen, earlier-indexed elements, so a pruned dd can never be in the global
// top-3; strict '<' keeps jax.lax.top_k's first-seen tie rule.
#define TPB1 512
#define NPB1 64
#define CHUNK 2048

__global__ __launch_bounds__(TPB1, 4) void knn_kernel(
    const float* __restrict__ coords,      // [B,N,3]
    const float* __restrict__ ref_coords,  // [B,M,3]
    int4* __restrict__ wsI,                // [B,N] {i0,i1,i2,-}
    float4* __restrict__ wsW)              // [B,N] {w0,w1,w2,-}
{
#pragma clang fp contract(off)
    __shared__ float4 refs[CHUNK];      // 32 KB (2x, 2y, 2z, rr)

    const int tid = threadIdx.x;
    const int b   = blockIdx.y;
    const int n0  = blockIdx.x * NPB1;

    const int pl = tid >> 3;            // point-in-block 0..63
    const int s  = tid & 7;             // sub-lane 0..7
    const int n  = n0 + pl;

    const float* cp = coords + ((size_t)b * NN + n) * 3;
    const float cx = cp[0];
    const float cy = cp[1];
    const float cz = cp[2];
    const float cc = (cx * cx + cy * cy) + cz * cz;   // numpy sum order

    float d0 = INFINITY, d1 = INFINITY, d2v = INFINITY;
    int   i0 = 0, i1 = 0, i2 = 0;
    float tau = INFINITY;               // group pruning threshold
    float thr = INFINITY;               // min(d2v, tau), kept in a register

    const float* rc = ref_coords + (size_t)b * MM * 3;

    for (int ch = 0; ch < MM / CHUNK; ++ch) {
        __syncthreads();                 // refs[] reuse guard
        for (int e = tid; e < CHUNK; e += TPB1) {
            const int j = ch * CHUNK + e;
            const float x = rc[3 * j + 0];
            const float y = rc[3 * j + 1];
            const float z = rc[3 * j + 2];
            // rr from ORIGINAL coords (numpy order); xyz pre-doubled (exact)
            refs[e] = make_float4(x + x, y + y, z + z, (x * x + y * y) + z * z);
        }
        __syncthreads();

        const int jbase = ch * CHUNK;
        for (int it0 = 0; it0 < CHUNK / 8; it0 += 32) {
            #pragma unroll 4
            for (int k = 0; k < 32; ++k) {
                const int e = s + ((it0 + k) << 3);
                const float4 r = refs[e];
                // dot2 == 2*((cx*rx + cy*ry) + cz*rz) bit-exactly
                const float dot2 = (cx * r.x + cy * r.y) + cz * r.z;
                const float dd   = (cc + r.w) - dot2;        // == numpy d2
                // Wave-uniform skip: if no lane beats its threshold, every
                // lane's dd is provably dead (>= d2v local no-op, or >= tau
                // globally dominated). Body is the ORIGINAL exact update.
                if (__any(dd < thr)) {
                    const int j = jbase + e;
                    const bool l2 = dd < d2v;
                    const bool l1 = dd < d1;
                    const bool l0 = dd < d0;
                    i2 = l2 ? (l1 ? i1 : j) : i2;
                    i1 = l1 ? (l0 ? i0 : j) : i1;
                    i0 = l0 ? j : i0;
                    const float n2  = __builtin_amdgcn_fmed3f(dd, d1, d2v);
                    const float n1  = __builtin_amdgcn_fmed3f(dd, d0, d1);
                    const float nv0 = fminf(dd, d0);
                    d2v = n2; d1 = n1; d0 = nv0;
                    thr = fminf(d2v, tau);
                }
            }
            // refresh tau = min of the 8 lanes' (same query) d2v
            float t = d2v;
            t = fminf(t, __shfl_xor(t, 1, 64));
            t = fminf(t, __shfl_xor(t, 2, 64));
            t = fminf(t, __shfl_xor(t, 4, 64));
            tau = t;
            thr = fminf(d2v, tau);
        }
    }

    // lexicographic (d, idx) insert: lower index wins exact ties (stable top_k)
    auto ins = [&](float e, int f) {
        const bool l2 = (e < d2v) || (e == d2v && f < i2);
        const bool l1 = (e < d1)  || (e == d1  && f < i1);
        const bool l0 = (e < d0)  || (e == d0  && f < i0);
        d2v = l2 ? (l1 ? d1 : e) : d2v;  i2 = l2 ? (l1 ? i1 : f) : i2;
        d1  = l1 ? (l0 ? d0 : e) : d1;   i1 = l1 ? (l0 ? i0 : f) : i1;
        d0  = l0 ? e : d0;               i0 = l0 ? f : i0;
    };

    // butterfly across the 8 sub-lanes (xor<8 stays in-group, in-wave)
    for (int off = 1; off < 8; off <<= 1) {
        const float e0 = __shfl_xor(d0,  off, 64);
        const float e1 = __shfl_xor(d1,  off, 64);
        const float e2 = __shfl_xor(d2v, off, 64);
        const int   f0 = __shfl_xor(i0,  off, 64);
        const int   f1 = __shfl_xor(i1,  off, 64);
        const int   f2 = __shfl_xor(i2,  off, 64);
        ins(e0, f0);
        ins(e1, f1);
        ins(e2, f2);
    }

    if (s == 0) {
        float w0 = 1.0f / (d0  + 1e-8f);     // IEEE divs, numpy order
        float w1 = 1.0f / (d1  + 1e-8f);
        float w2 = 1.0f / (d2v + 1e-8f);
        const float sum = (w0 + w1) + w2;
        wsI[(size_t)b * NN + n] = make_int4(i0, i1, i2, 0);
        wsW[(size_t)b * NN + n] = make_float4(w0 / sum, w1 / sum, w2 / sum, 0.0f);
    }
}

// ===================== kernel 2: row-staged interpolation ====================
// One block per output row. The 16 KB source row is staged in LDS ONCE (each
// row fetched from HBM exactly once), then all 16384 queries gather from LDS
// (random ds_read_b32 ~3-4-way conflicts << L1 scatter cost). idx/w loads are
// coalesced 32 B/query from the 2 MB workspace (L2-resident). pf rows are
// pure-copy blocks. Same fma order as before (contract off) for bit-identical
// interpolation.
#define TPB2 256

__global__ __launch_bounds__(TPB2, 8) void interp_kernel(
    const float* __restrict__ refF,        // [B,256,M]
    const float* __restrict__ refT,        // [B,128,M]
    const float* __restrict__ pf,          // [B,64,N]
    const int4*  __restrict__ wsI,         // [B,N]
    const float4* __restrict__ wsW,        // [B,N]
    float* __restrict__ out)               // [B,320,N] ++ [B,128,N]
{
#pragma clang fp contract(off)
    __shared__ float row[MM];              // 16 KB
    const int tid  = threadIdx.x;
    const int task = blockIdx.x;
    const size_t outT_base = (size_t)BB * (CF + CP) * NN;

    const float* src;
    float* dst;
    int b;
    if (task < BB * CF) {                          // interpolated features
        b = task >> 8;                             // / CF
        const int c = task & (CF - 1);
        src = refF + ((size_t)b * CF + c) * MM;
        dst = out + ((size_t)b * (CF + CP) + c) * NN;
    } else if (task < BB * (CF + CT)) {            // interpolated t_embed
        const int t2 = task - BB * CF;
        b = t2 >> 7;                               // / CT
        const int c = t2 & (CT - 1);
        src = refT + ((size_t)b * CT + c) * MM;
        dst = out + outT_base + ((size_t)b * CT + c) * NN;
    } else {                                       // skip-feature copy rows
        const int t3 = task - BB * (CF + CT);
        const int bb = t3 >> 6;                    // / CP
        const int c  = t3 & (CP - 1);
        const float4* s4 = (const float4*)(pf + ((size_t)bb * CP + c) * NN);
        float4* d4 = (float4*)(out + ((size_t)bb * (CF + CP) + CF + c) * NN);
        for (int i = tid; i < NN / 4; i += TPB2) d4[i] = s4[i];
        return;                                    // block-uniform exit
    }

    for (int i = tid; i < MM / 4; i += TPB2)
        ((float4*)row)[i] = ((const float4*)src)[i];
    __syncthreads();

    const int4*  wi = wsI + (size_t)b * NN;
    const float4* ww = wsW + (size_t)b * NN;
    for (int nq = tid; nq < NN; nq += TPB2) {
        const int4  id = wi[nq];
        const float4 w = ww[nq];
        dst[nq] = (w.x * row[id.x] + w.y * row[id.y]) + w.z * row[id.z];
    }
}

extern "C" void kernel_launch(void* const* d_in, const int* in_sizes, int n_in,
                              void* d_out, int out_size, void* d_ws, size_t ws_size,
                              hipStream_t stream) {
    const float* coords     = (const float*)d_in[0];
    const float* ref_coords = (const float*)d_in[1];
    const float* refF       = (const float*)d_in[2];
    const float* refT       = (const float*)d_in[3];
    const float* pf         = (const float*)d_in[4];
    float* out = (float*)d_out;

    int4*   wsI = (int4*)d_ws;
    float4* wsW = (float4*)((char*)d_ws + (size_t)BB * NN * sizeof(int4));

    hipLaunchKernelGGL(knn_kernel, dim3(NN / NPB1, BB), dim3(TPB1), 0, stream,
                       coords, ref_coords, wsI, wsW);
    hipLaunchKernelGGL(interp_kernel, dim3(BB * (CF + CT + CP)), dim3(TPB2), 0, stream,
                       refF, refT, pf, wsI, wsW, out);
}